// Round 1
// baseline (865.854 us; speedup 1.0000x reference)
//
#include <hip/hip_runtime.h>
#include <hip/hip_bf16.h>
#include <math.h>

#define T_STEPS 8
#define F_IN 64
#define HC 128        // H*C = 2*64
#define C_OUT 64
#define NEG_SLOPE 0.2f

// ---------------- CSR build ----------------
__global__ void k_zero_i32(int* p, int n) {
    int i = blockIdx.x * blockDim.x + threadIdx.x;
    if (i < n) p[i] = 0;
}

__global__ void k_count(const int* __restrict__ dst, int* __restrict__ cnt, int E) {
    int e = blockIdx.x * blockDim.x + threadIdx.x;
    if (e < E) atomicAdd(&cnt[dst[e]], 1);
}

// per-block exclusive scan (in place), block totals to bsum
__global__ void k_scan1(int* data, int* bsum, int n) {
    __shared__ int tmp[256];
    int tid = threadIdx.x;
    int i = blockIdx.x * 256 + tid;
    int v = (i < n) ? data[i] : 0;
    tmp[tid] = v; __syncthreads();
    for (int off = 1; off < 256; off <<= 1) {
        int x = (tid >= off) ? tmp[tid - off] : 0;
        __syncthreads();
        tmp[tid] += x;
        __syncthreads();
    }
    if (i < n) data[i] = tmp[tid] - v;   // exclusive
    if (tid == 255) bsum[blockIdx.x] = tmp[255];
}

__global__ void k_scan2(int* bsum, int nb) {  // nb <= 256 (N=50000 -> 196 blocks)
    __shared__ int tmp[256];
    int tid = threadIdx.x;
    int v = (tid < nb) ? bsum[tid] : 0;
    tmp[tid] = v; __syncthreads();
    for (int off = 1; off < 256; off <<= 1) {
        int x = (tid >= off) ? tmp[tid - off] : 0;
        __syncthreads();
        tmp[tid] += x;
        __syncthreads();
    }
    if (tid < nb) bsum[tid] = tmp[tid] - v;
}

__global__ void k_scan3(int* data, const int* __restrict__ bsum, int* cursor, int n, int total) {
    int i = blockIdx.x * 256 + threadIdx.x;
    if (i < n) {
        int v = data[i] + bsum[i >> 8];
        data[i] = v;
        cursor[i] = v;
    }
    if (i == 0) data[n] = total;
}

__global__ void k_fill(const int* __restrict__ src, const int* __restrict__ dst,
                       int* __restrict__ cursor, int* __restrict__ csr_src, int E) {
    int e = blockIdx.x * blockDim.x + threadIdx.x;
    if (e < E) {
        int d = dst[e];
        int pos = atomicAdd(&cursor[d], 1);
        csr_src[pos] = src[e];
    }
}

// ---------------- GEMM: xl = x_t @ W, plus attention scores ----------------
// Block: 256 threads, 64-node tile. LDS: W[64][128] (32KB) + xT[64][64] (16KB).
// Thread (tx=tid&31, ty=tid>>5) computes 8 nodes x 4 cols.
__global__ __launch_bounds__(256) void k_gemm(
    const float* __restrict__ h, const float* __restrict__ W,
    const float* __restrict__ att_src, const float* __restrict__ att_dst,
    float* __restrict__ xl, float* __restrict__ a_s, float* __restrict__ a_d,
    int N, int t_base)
{
    __shared__ float sW[F_IN * HC];
    __shared__ float sX[F_IN * 64];   // transposed: sX[f*64 + node_local]
    __shared__ float sAS[HC], sAD[HC];

    int tid = threadIdx.x;
    int by = blockIdx.y;
    int t = t_base + by;
    int node0 = blockIdx.x * 64;

    for (int i = tid * 4; i < F_IN * HC; i += 1024)
        *(float4*)&sW[i] = *(const float4*)&W[i];
    if (tid < HC) { sAS[tid] = att_src[tid]; sAD[tid] = att_dst[tid]; }

    for (int u = tid; u < 64 * 16; u += 256) {
        int nl = u >> 4;
        int f4 = u & 15;
        int n = node0 + nl;
        float4 v = make_float4(0.f, 0.f, 0.f, 0.f);
        if (n < N) v = *(const float4*)&h[(n * T_STEPS + t) * F_IN + f4 * 4];
        sX[(f4 * 4 + 0) * 64 + nl] = v.x;
        sX[(f4 * 4 + 1) * 64 + nl] = v.y;
        sX[(f4 * 4 + 2) * 64 + nl] = v.z;
        sX[(f4 * 4 + 3) * 64 + nl] = v.w;
    }
    __syncthreads();

    int tx = tid & 31;
    int ty = tid >> 5;
    float acc[8][4];
    #pragma unroll
    for (int i = 0; i < 8; i++)
        #pragma unroll
        for (int j = 0; j < 4; j++) acc[i][j] = 0.f;

    #pragma unroll 4
    for (int f = 0; f < F_IN; f++) {
        float4 wv = *(float4*)&sW[f * HC + tx * 4];
        float4 xa = *(float4*)&sX[f * 64 + ty * 8];
        float4 xb = *(float4*)&sX[f * 64 + ty * 8 + 4];
        float xs[8] = {xa.x, xa.y, xa.z, xa.w, xb.x, xb.y, xb.z, xb.w};
        #pragma unroll
        for (int i = 0; i < 8; i++) {
            acc[i][0] += xs[i] * wv.x;
            acc[i][1] += xs[i] * wv.y;
            acc[i][2] += xs[i] * wv.z;
            acc[i][3] += xs[i] * wv.w;
        }
    }

    float4 vs = *(float4*)&sAS[tx * 4];
    float4 vd = *(float4*)&sAD[tx * 4];
    size_t baseN = (size_t)by * N;
    #pragma unroll
    for (int i = 0; i < 8; i++) {
        int n = node0 + ty * 8 + i;
        if (n < N) {
            *(float4*)&xl[(baseN + n) * HC + tx * 4] =
                make_float4(acc[i][0], acc[i][1], acc[i][2], acc[i][3]);
        }
        float ps = acc[i][0] * vs.x + acc[i][1] * vs.y + acc[i][2] * vs.z + acc[i][3] * vs.w;
        float pd = acc[i][0] * vd.x + acc[i][1] * vd.y + acc[i][2] * vd.z + acc[i][3] * vd.w;
        #pragma unroll
        for (int off = 8; off >= 1; off >>= 1) {
            ps += __shfl_down(ps, off, 16);
            pd += __shfl_down(pd, off, 16);
        }
        if ((tx & 15) == 0 && n < N) {
            int hh = tx >> 4;
            a_s[(baseN + n) * 2 + hh] = ps;
            a_d[(baseN + n) * 2 + hh] = pd;
        }
    }
}

// ---------------- Edge softmax + aggregate (one wave per node) ----------------
__global__ __launch_bounds__(256) void k_edge(
    const int* __restrict__ csr_row, const int* __restrict__ csr_src,
    const float* __restrict__ a_s, const float* __restrict__ a_d,
    const float* __restrict__ xl, const float* __restrict__ bias,
    float* __restrict__ out, int N, int t_base)
{
    int lane = threadIdx.x & 63;
    int wid = threadIdx.x >> 6;
    int by = blockIdx.y;
    int n = blockIdx.x * 4 + wid;
    if (n >= N) return;

    size_t baseN = (size_t)by * N;
    int beg = csr_row[n], end = csr_row[n + 1];
    float ad0 = a_d[(baseN + n) * 2 + 0];
    float ad1 = a_d[(baseN + n) * 2 + 1];

    // pass 1: per-head max of leaky_relu scores
    float m0 = -1e30f, m1 = -1e30f;
    for (int e = beg + lane; e < end; e += 64) {
        int s = csr_src[e];
        float e0 = a_s[(baseN + s) * 2 + 0] + ad0;
        float e1 = a_s[(baseN + s) * 2 + 1] + ad1;
        e0 = e0 > 0.f ? e0 : NEG_SLOPE * e0;
        e1 = e1 > 0.f ? e1 : NEG_SLOPE * e1;
        m0 = fmaxf(m0, e0);
        m1 = fmaxf(m1, e1);
    }
    #pragma unroll
    for (int off = 32; off >= 1; off >>= 1) {
        m0 = fmaxf(m0, __shfl_xor(m0, off));
        m1 = fmaxf(m1, __shfl_xor(m1, off));
    }

    // pass 2: denominators
    float d0 = 0.f, d1 = 0.f;
    for (int e = beg + lane; e < end; e += 64) {
        int s = csr_src[e];
        float e0 = a_s[(baseN + s) * 2 + 0] + ad0;
        float e1 = a_s[(baseN + s) * 2 + 1] + ad1;
        e0 = e0 > 0.f ? e0 : NEG_SLOPE * e0;
        e1 = e1 > 0.f ? e1 : NEG_SLOPE * e1;
        d0 += __expf(e0 - m0);
        d1 += __expf(e1 - m1);
    }
    #pragma unroll
    for (int off = 32; off >= 1; off >>= 1) {
        d0 += __shfl_xor(d0, off);
        d1 += __shfl_xor(d1, off);
    }
    float r0 = 0.5f / d0;   // includes head-mean 1/2
    float r1 = 0.5f / d1;

    // pass 3: aggregate; lane == output channel c
    float acc = 0.f;
    for (int e = beg; e < end; e++) {
        int s = csr_src[e];
        float e0 = a_s[(baseN + s) * 2 + 0] + ad0;
        float e1 = a_s[(baseN + s) * 2 + 1] + ad1;
        e0 = e0 > 0.f ? e0 : NEG_SLOPE * e0;
        e1 = e1 > 0.f ? e1 : NEG_SLOPE * e1;
        float w0 = __expf(e0 - m0) * r0;
        float w1 = __expf(e1 - m1) * r1;
        const float* xr = &xl[(baseN + s) * HC];
        acc += w0 * xr[lane] + w1 * xr[64 + lane];
    }
    acc += bias[lane];
    float o = acc > 0.f ? acc : expm1f(acc);
    out[((size_t)n * T_STEPS + (t_base + by)) * C_OUT + lane] = o;
}

// ---------------- launcher ----------------
extern "C" void kernel_launch(void* const* d_in, const int* in_sizes, int n_in,
                              void* d_out, int out_size, void* d_ws, size_t ws_size,
                              hipStream_t stream)
{
    const float* h       = (const float*)d_in[0];
    const int*   src     = (const int*)d_in[1];
    const int*   dst     = (const int*)d_in[2];
    const float* W       = (const float*)d_in[3];
    const float* att_src = (const float*)d_in[4];
    const float* att_dst = (const float*)d_in[5];
    const float* bias    = (const float*)d_in[6];
    float* out = (float*)d_out;

    int N = in_sizes[0] / (T_STEPS * F_IN);
    int E = in_sizes[1];

    char* wsb = (char*)d_ws;
    size_t off = 0;
    auto alloc = [&](size_t bytes) -> char* {
        off = (off + 255) & ~(size_t)255;
        char* p = wsb + off;
        off += bytes;
        return p;
    };

    int* csr_row = (int*)alloc((size_t)(N + 1) * sizeof(int));
    int* cursor  = (int*)alloc((size_t)N * sizeof(int));
    int* bsum    = (int*)alloc(1024 * sizeof(int));
    int* csr_src = (int*)alloc((size_t)E * sizeof(int));

    // timestep chunking adapted to workspace size (ws_size constant -> deterministic)
    size_t per_t = (size_t)N * (HC + 4) * sizeof(float) + 1024;
    size_t avail = (ws_size > off + 4096) ? (ws_size - off - 4096) : 0;
    int TC = (int)(avail / per_t);
    if (TC < 1) TC = 1;
    if (TC > T_STEPS) TC = T_STEPS;

    float* a_s = (float*)alloc((size_t)TC * N * 2 * sizeof(float));
    float* a_d = (float*)alloc((size_t)TC * N * 2 * sizeof(float));
    float* xl  = (float*)alloc((size_t)TC * N * HC * sizeof(float));

    int nb = (N + 255) / 256;   // 196 for N=50000 (must be <= 256 for k_scan2)
    k_zero_i32<<<(N + 1 + 255) / 256, 256, 0, stream>>>(csr_row, N + 1);
    k_count<<<(E + 255) / 256, 256, 0, stream>>>(dst, csr_row, E);
    k_scan1<<<nb, 256, 0, stream>>>(csr_row, bsum, N);
    k_scan2<<<1, 256, 0, stream>>>(bsum, nb);
    k_scan3<<<nb, 256, 0, stream>>>(csr_row, bsum, cursor, N, E);
    k_fill<<<(E + 255) / 256, 256, 0, stream>>>(src, dst, cursor, csr_src, E);

    for (int t0 = 0; t0 < T_STEPS; t0 += TC) {
        int tc = T_STEPS - t0 < TC ? T_STEPS - t0 : TC;
        dim3 gg((N + 63) / 64, tc);
        k_gemm<<<gg, 256, 0, stream>>>(h, W, att_src, att_dst, xl, a_s, a_d, N, t0);
        dim3 ge((N + 3) / 4, tc);
        k_edge<<<ge, 256, 0, stream>>>(csr_row, csr_src, a_s, a_d, xl, bias, out, N, t0);
    }
}

// Round 2
// 765.375 us; speedup vs baseline: 1.1313x; 1.1313x over previous
//
#include <hip/hip_runtime.h>
#include <hip/hip_bf16.h>
#include <math.h>

#define T_STEPS 8
#define F_IN 64
#define HC 128        // H*C = 2*64
#define C_OUT 64
#define NEG_SLOPE 0.2f

typedef _Float16 half8 __attribute__((ext_vector_type(8)));
typedef _Float16 half2v __attribute__((ext_vector_type(2)));

// ---------------- CSR build ----------------
__global__ void k_zero_i32(int* p, int n) {
    int i = blockIdx.x * blockDim.x + threadIdx.x;
    if (i < n) p[i] = 0;
}

__global__ void k_count(const int* __restrict__ dst, int* __restrict__ cnt, int E) {
    int e = blockIdx.x * blockDim.x + threadIdx.x;
    if (e < E) atomicAdd(&cnt[dst[e]], 1);
}

// per-block exclusive scan (in place), block totals to bsum
__global__ void k_scan1(int* data, int* bsum, int n) {
    __shared__ int tmp[256];
    int tid = threadIdx.x;
    int i = blockIdx.x * 256 + tid;
    int v = (i < n) ? data[i] : 0;
    tmp[tid] = v; __syncthreads();
    for (int off = 1; off < 256; off <<= 1) {
        int x = (tid >= off) ? tmp[tid - off] : 0;
        __syncthreads();
        tmp[tid] += x;
        __syncthreads();
    }
    if (i < n) data[i] = tmp[tid] - v;   // exclusive
    if (tid == 255) bsum[blockIdx.x] = tmp[255];
}

__global__ void k_scan2(int* bsum, int nb) {  // nb <= 256 (N=50000 -> 196 blocks)
    __shared__ int tmp[256];
    int tid = threadIdx.x;
    int v = (tid < nb) ? bsum[tid] : 0;
    tmp[tid] = v; __syncthreads();
    for (int off = 1; off < 256; off <<= 1) {
        int x = (tid >= off) ? tmp[tid - off] : 0;
        __syncthreads();
        tmp[tid] += x;
        __syncthreads();
    }
    if (tid < nb) bsum[tid] = tmp[tid] - v;
}

__global__ void k_scan3(int* data, const int* __restrict__ bsum, int* cursor, int n, int total) {
    int i = blockIdx.x * 256 + threadIdx.x;
    if (i < n) {
        int v = data[i] + bsum[i >> 8];
        data[i] = v;
        cursor[i] = v;
    }
    if (i == 0) data[n] = total;
}

__global__ void k_fill(const int* __restrict__ src, const int* __restrict__ dst,
                       int* __restrict__ cursor, int* __restrict__ csr_src, int E) {
    int e = blockIdx.x * blockDim.x + threadIdx.x;
    if (e < E) {
        int d = dst[e];
        int pos = atomicAdd(&cursor[d], 1);
        csr_src[pos] = src[e];
    }
}

// ---------------- GEMM: xl = x_t @ W (fp16 head-interleaved out) + scores ----
// Block: 256 threads, 64-node tile. Thread (tx=tid&31, ty=tid>>5): 8 nodes x 4 cols.
// xlh row layout: 128 halfs, index c*2 + h  (c in [0,64), h in {0,1})
__global__ __launch_bounds__(256) void k_gemm(
    const float* __restrict__ h, const float* __restrict__ W,
    const float* __restrict__ att_src, const float* __restrict__ att_dst,
    _Float16* __restrict__ xlh, float* __restrict__ a_s, float* __restrict__ a_d,
    int N, int t)
{
    __shared__ float sW[F_IN * HC];
    __shared__ float sX[F_IN * 64];   // transposed: sX[f*64 + node_local]
    __shared__ float sAS[HC], sAD[HC];

    int tid = threadIdx.x;
    int node0 = blockIdx.x * 64;

    for (int i = tid * 4; i < F_IN * HC; i += 1024)
        *(float4*)&sW[i] = *(const float4*)&W[i];
    if (tid < HC) { sAS[tid] = att_src[tid]; sAD[tid] = att_dst[tid]; }

    for (int u = tid; u < 64 * 16; u += 256) {
        int nl = u >> 4;
        int f4 = u & 15;
        int n = node0 + nl;
        float4 v = make_float4(0.f, 0.f, 0.f, 0.f);
        if (n < N) v = *(const float4*)&h[(n * T_STEPS + t) * F_IN + f4 * 4];
        sX[(f4 * 4 + 0) * 64 + nl] = v.x;
        sX[(f4 * 4 + 1) * 64 + nl] = v.y;
        sX[(f4 * 4 + 2) * 64 + nl] = v.z;
        sX[(f4 * 4 + 3) * 64 + nl] = v.w;
    }
    __syncthreads();

    int tx = tid & 31;
    int ty = tid >> 5;
    int lane = tid & 63;
    float acc[8][4];
    #pragma unroll
    for (int i = 0; i < 8; i++)
        #pragma unroll
        for (int j = 0; j < 4; j++) acc[i][j] = 0.f;

    #pragma unroll 4
    for (int f = 0; f < F_IN; f++) {
        float4 wv = *(float4*)&sW[f * HC + tx * 4];
        float4 xa = *(float4*)&sX[f * 64 + ty * 8];
        float4 xb = *(float4*)&sX[f * 64 + ty * 8 + 4];
        float xs[8] = {xa.x, xa.y, xa.z, xa.w, xb.x, xb.y, xb.z, xb.w};
        #pragma unroll
        for (int i = 0; i < 8; i++) {
            acc[i][0] += xs[i] * wv.x;
            acc[i][1] += xs[i] * wv.y;
            acc[i][2] += xs[i] * wv.z;
            acc[i][3] += xs[i] * wv.w;
        }
    }

    float4 vs = *(float4*)&sAS[tx * 4];
    float4 vd = *(float4*)&sAD[tx * 4];
    #pragma unroll
    for (int i = 0; i < 8; i++) {
        int n = node0 + ty * 8 + i;
        // head-partner exchange: thread tx (<16, head0 col c=tx*4+j) pairs with
        // tx+16 (head1, same c) — partner is lane+16 within the wave.
        float p0 = __shfl(acc[i][0], (lane + 16) & 63);
        float p1 = __shfl(acc[i][1], (lane + 16) & 63);
        float p2 = __shfl(acc[i][2], (lane + 16) & 63);
        float p3 = __shfl(acc[i][3], (lane + 16) & 63);
        if (tx < 16 && n < N) {
            half8 v;
            v[0] = (_Float16)acc[i][0]; v[1] = (_Float16)p0;
            v[2] = (_Float16)acc[i][1]; v[3] = (_Float16)p1;
            v[4] = (_Float16)acc[i][2]; v[5] = (_Float16)p2;
            v[6] = (_Float16)acc[i][3]; v[7] = (_Float16)p3;
            *(half8*)&xlh[n * HC + tx * 8] = v;
        }
        float ps = acc[i][0] * vs.x + acc[i][1] * vs.y + acc[i][2] * vs.z + acc[i][3] * vs.w;
        float pd = acc[i][0] * vd.x + acc[i][1] * vd.y + acc[i][2] * vd.z + acc[i][3] * vd.w;
        #pragma unroll
        for (int off = 8; off >= 1; off >>= 1) {
            ps += __shfl_down(ps, off, 16);
            pd += __shfl_down(pd, off, 16);
        }
        if ((tx & 15) == 0 && n < N) {
            int hh = tx >> 4;
            a_s[(size_t)n * 2 + hh] = ps;
            a_d[(size_t)n * 2 + hh] = pd;
        }
    }
}

// ---------------- Edge softmax + aggregate (one wave per node, one t) -------
__global__ __launch_bounds__(256) void k_edge(
    const int* __restrict__ csr_row, const int* __restrict__ csr_src,
    const float* __restrict__ a_s, const float* __restrict__ a_d,
    const _Float16* __restrict__ xlh, const float* __restrict__ bias,
    float* __restrict__ out, int N, int t)
{
    int lane = threadIdx.x & 63;
    int wid = threadIdx.x >> 6;
    int n = blockIdx.x * 4 + wid;
    if (n >= N) return;

    int beg = csr_row[n], end = csr_row[n + 1];
    int deg = end - beg;
    float2 adv = *(const float2*)&a_d[(size_t)n * 2];

    float acc0 = 0.f, acc1 = 0.f;

    if (deg <= 64) {
        // fast path: one edge per lane, scores computed exactly once
        int e = beg + lane;
        bool valid = e < end;
        int s = valid ? csr_src[e] : 0;
        float e0 = -1e30f, e1 = -1e30f;
        if (valid) {
            float2 asv = *(const float2*)&a_s[(size_t)s * 2];
            e0 = asv.x + adv.x;
            e1 = asv.y + adv.y;
            e0 = e0 > 0.f ? e0 : NEG_SLOPE * e0;
            e1 = e1 > 0.f ? e1 : NEG_SLOPE * e1;
        }
        float m0 = e0, m1 = e1;
        #pragma unroll
        for (int off = 32; off >= 1; off >>= 1) {
            m0 = fmaxf(m0, __shfl_xor(m0, off));
            m1 = fmaxf(m1, __shfl_xor(m1, off));
        }
        float x0 = valid ? __expf(e0 - m0) : 0.f;
        float x1 = valid ? __expf(e1 - m1) : 0.f;
        float d0 = x0, d1 = x1;
        #pragma unroll
        for (int off = 32; off >= 1; off >>= 1) {
            d0 += __shfl_xor(d0, off);
            d1 += __shfl_xor(d1, off);
        }
        float w0 = x0 * (0.5f / d0);   // 0.5 = head-mean
        float w1 = x1 * (0.5f / d1);
        for (int j = 0; j < deg; j++) {
            int sj = __shfl(s, j);
            float w0j = __shfl(w0, j);
            float w1j = __shfl(w1, j);
            half2v v = *(const half2v*)&xlh[sj * HC + lane * 2];
            acc0 = fmaf(w0j, (float)v.x, acc0);
            acc1 = fmaf(w1j, (float)v.y, acc1);
        }
    } else {
        // generic path (deg > 64): strided max + sum, then chunked broadcast
        float m0 = -1e30f, m1 = -1e30f;
        for (int e = beg + lane; e < end; e += 64) {
            int s = csr_src[e];
            float2 asv = *(const float2*)&a_s[(size_t)s * 2];
            float e0 = asv.x + adv.x, e1 = asv.y + adv.y;
            e0 = e0 > 0.f ? e0 : NEG_SLOPE * e0;
            e1 = e1 > 0.f ? e1 : NEG_SLOPE * e1;
            m0 = fmaxf(m0, e0); m1 = fmaxf(m1, e1);
        }
        #pragma unroll
        for (int off = 32; off >= 1; off >>= 1) {
            m0 = fmaxf(m0, __shfl_xor(m0, off));
            m1 = fmaxf(m1, __shfl_xor(m1, off));
        }
        float d0 = 0.f, d1 = 0.f;
        for (int e = beg + lane; e < end; e += 64) {
            int s = csr_src[e];
            float2 asv = *(const float2*)&a_s[(size_t)s * 2];
            float e0 = asv.x + adv.x, e1 = asv.y + adv.y;
            e0 = e0 > 0.f ? e0 : NEG_SLOPE * e0;
            e1 = e1 > 0.f ? e1 : NEG_SLOPE * e1;
            d0 += __expf(e0 - m0); d1 += __expf(e1 - m1);
        }
        #pragma unroll
        for (int off = 32; off >= 1; off >>= 1) {
            d0 += __shfl_xor(d0, off);
            d1 += __shfl_xor(d1, off);
        }
        float r0 = 0.5f / d0, r1 = 0.5f / d1;
        for (int base = beg; base < end; base += 64) {
            int e = base + lane;
            int cnt = min(64, end - base);
            int s = 0; float w0 = 0.f, w1 = 0.f;
            if (e < end) {
                s = csr_src[e];
                float2 asv = *(const float2*)&a_s[(size_t)s * 2];
                float e0 = asv.x + adv.x, e1 = asv.y + adv.y;
                e0 = e0 > 0.f ? e0 : NEG_SLOPE * e0;
                e1 = e1 > 0.f ? e1 : NEG_SLOPE * e1;
                w0 = __expf(e0 - m0) * r0;
                w1 = __expf(e1 - m1) * r1;
            }
            for (int j = 0; j < cnt; j++) {
                int sj = __shfl(s, j);
                float w0j = __shfl(w0, j);
                float w1j = __shfl(w1, j);
                half2v v = *(const half2v*)&xlh[sj * HC + lane * 2];
                acc0 = fmaf(w0j, (float)v.x, acc0);
                acc1 = fmaf(w1j, (float)v.y, acc1);
            }
        }
    }

    float acc = acc0 + acc1 + bias[lane];
    float o = acc > 0.f ? acc : expm1f(acc);
    out[((size_t)n * T_STEPS + t) * C_OUT + lane] = o;
}

// ---------------- launcher ----------------
extern "C" void kernel_launch(void* const* d_in, const int* in_sizes, int n_in,
                              void* d_out, int out_size, void* d_ws, size_t ws_size,
                              hipStream_t stream)
{
    const float* h       = (const float*)d_in[0];
    const int*   src     = (const int*)d_in[1];
    const int*   dst     = (const int*)d_in[2];
    const float* W       = (const float*)d_in[3];
    const float* att_src = (const float*)d_in[4];
    const float* att_dst = (const float*)d_in[5];
    const float* bias    = (const float*)d_in[6];
    float* out = (float*)d_out;

    int N = in_sizes[0] / (T_STEPS * F_IN);
    int E = in_sizes[1];

    char* wsb = (char*)d_ws;
    size_t off = 0;
    auto alloc = [&](size_t bytes) -> char* {
        off = (off + 255) & ~(size_t)255;
        char* p = wsb + off;
        off += bytes;
        return p;
    };

    int* csr_row = (int*)alloc((size_t)(N + 1) * sizeof(int));
    int* cursor  = (int*)alloc((size_t)N * sizeof(int));
    int* bsum    = (int*)alloc(1024 * sizeof(int));
    int* csr_src = (int*)alloc((size_t)E * sizeof(int));
    float* a_s   = (float*)alloc((size_t)N * 2 * sizeof(float));
    float* a_d   = (float*)alloc((size_t)N * 2 * sizeof(float));
    _Float16* xlh = (_Float16*)alloc((size_t)N * HC * sizeof(_Float16));

    int nb = (N + 255) / 256;   // 196 for N=50000 (must be <= 256 for k_scan2)
    k_zero_i32<<<(N + 1 + 255) / 256, 256, 0, stream>>>(csr_row, N + 1);
    k_count<<<(E + 255) / 256, 256, 0, stream>>>(dst, csr_row, E);
    k_scan1<<<nb, 256, 0, stream>>>(csr_row, bsum, N);
    k_scan2<<<1, 256, 0, stream>>>(bsum, nb);
    k_scan3<<<nb, 256, 0, stream>>>(csr_row, bsum, cursor, N, E);
    k_fill<<<(E + 255) / 256, 256, 0, stream>>>(src, dst, cursor, csr_src, E);

    // one timestep at a time: per-t gather working set (12.8 MB fp16 xl)
    // stays L2/L3-resident instead of thrashing the 256 MB L3 with 8 t at once
    for (int t = 0; t < T_STEPS; t++) {
        k_gemm<<<(N + 63) / 64, 256, 0, stream>>>(h, W, att_src, att_dst,
                                                  xlh, a_s, a_d, N, t);
        k_edge<<<(N + 3) / 4, 256, 0, stream>>>(csr_row, csr_src, a_s, a_d,
                                                xlh, bias, out, N, t);
    }
}

// Round 3
// 736.171 us; speedup vs baseline: 1.1762x; 1.0397x over previous
//
#include <hip/hip_runtime.h>
#include <hip/hip_bf16.h>
#include <math.h>

#define T_STEPS 8
#define F_IN 64
#define HC 128        // H*C = 2*64
#define C_OUT 64
#define NEG_SLOPE 0.2f

typedef _Float16 half8 __attribute__((ext_vector_type(8)));
typedef _Float16 half2v __attribute__((ext_vector_type(2)));

// ---------------- CSR build ----------------
__global__ void k_zero_i32(int* p, int n) {
    int i = blockIdx.x * blockDim.x + threadIdx.x;
    if (i < n) p[i] = 0;
}

__global__ void k_count(const int* __restrict__ dst, int* __restrict__ cnt, int E) {
    int e = blockIdx.x * blockDim.x + threadIdx.x;
    if (e < E) atomicAdd(&cnt[dst[e]], 1);
}

__global__ void k_scan1(int* data, int* bsum, int n) {
    __shared__ int tmp[256];
    int tid = threadIdx.x;
    int i = blockIdx.x * 256 + tid;
    int v = (i < n) ? data[i] : 0;
    tmp[tid] = v; __syncthreads();
    for (int off = 1; off < 256; off <<= 1) {
        int x = (tid >= off) ? tmp[tid - off] : 0;
        __syncthreads();
        tmp[tid] += x;
        __syncthreads();
    }
    if (i < n) data[i] = tmp[tid] - v;   // exclusive
    if (tid == 255) bsum[blockIdx.x] = tmp[255];
}

__global__ void k_scan2(int* bsum, int nb) {  // nb <= 256
    __shared__ int tmp[256];
    int tid = threadIdx.x;
    int v = (tid < nb) ? bsum[tid] : 0;
    tmp[tid] = v; __syncthreads();
    for (int off = 1; off < 256; off <<= 1) {
        int x = (tid >= off) ? tmp[tid - off] : 0;
        __syncthreads();
        tmp[tid] += x;
        __syncthreads();
    }
    if (tid < nb) bsum[tid] = tmp[tid] - v;
}

__global__ void k_scan3(int* data, const int* __restrict__ bsum, int* cursor, int n, int total) {
    int i = blockIdx.x * 256 + threadIdx.x;
    if (i < n) {
        int v = data[i] + bsum[i >> 8];
        data[i] = v;
        cursor[i] = v;
    }
    if (i == 0) data[n] = total;
}

__global__ void k_fill(const int* __restrict__ src, const int* __restrict__ dst,
                       int* __restrict__ cursor, int* __restrict__ csr_src, int E) {
    int e = blockIdx.x * blockDim.x + threadIdx.x;
    if (e < E) {
        int d = dst[e];
        int pos = atomicAdd(&cursor[d], 1);
        csr_src[pos] = src[e];
    }
}

// ---------------- GEMM: xl = x_t @ W (fp16 head-interleaved out) + scores ----
__global__ __launch_bounds__(256) void k_gemm(
    const float* __restrict__ h, const float* __restrict__ W,
    const float* __restrict__ att_src, const float* __restrict__ att_dst,
    _Float16* __restrict__ xlh, float* __restrict__ a_s, float* __restrict__ a_d,
    int N, int t)
{
    __shared__ float sW[F_IN * HC];
    __shared__ float sX[F_IN * 64];   // transposed: sX[f*64 + node_local]
    __shared__ float sAS[HC], sAD[HC];

    int tid = threadIdx.x;
    int node0 = blockIdx.x * 64;

    for (int i = tid * 4; i < F_IN * HC; i += 1024)
        *(float4*)&sW[i] = *(const float4*)&W[i];
    if (tid < HC) { sAS[tid] = att_src[tid]; sAD[tid] = att_dst[tid]; }

    for (int u = tid; u < 64 * 16; u += 256) {
        int nl = u >> 4;
        int f4 = u & 15;
        int n = node0 + nl;
        float4 v = make_float4(0.f, 0.f, 0.f, 0.f);
        if (n < N) v = *(const float4*)&h[(n * T_STEPS + t) * F_IN + f4 * 4];
        sX[(f4 * 4 + 0) * 64 + nl] = v.x;
        sX[(f4 * 4 + 1) * 64 + nl] = v.y;
        sX[(f4 * 4 + 2) * 64 + nl] = v.z;
        sX[(f4 * 4 + 3) * 64 + nl] = v.w;
    }
    __syncthreads();

    int tx = tid & 31;
    int ty = tid >> 5;
    int lane = tid & 63;
    float acc[8][4];
    #pragma unroll
    for (int i = 0; i < 8; i++)
        #pragma unroll
        for (int j = 0; j < 4; j++) acc[i][j] = 0.f;

    #pragma unroll 4
    for (int f = 0; f < F_IN; f++) {
        float4 wv = *(float4*)&sW[f * HC + tx * 4];
        float4 xa = *(float4*)&sX[f * 64 + ty * 8];
        float4 xb = *(float4*)&sX[f * 64 + ty * 8 + 4];
        float xs[8] = {xa.x, xa.y, xa.z, xa.w, xb.x, xb.y, xb.z, xb.w};
        #pragma unroll
        for (int i = 0; i < 8; i++) {
            acc[i][0] += xs[i] * wv.x;
            acc[i][1] += xs[i] * wv.y;
            acc[i][2] += xs[i] * wv.z;
            acc[i][3] += xs[i] * wv.w;
        }
    }

    float4 vs = *(float4*)&sAS[tx * 4];
    float4 vd = *(float4*)&sAD[tx * 4];
    #pragma unroll
    for (int i = 0; i < 8; i++) {
        int n = node0 + ty * 8 + i;
        float p0 = __shfl(acc[i][0], (lane + 16) & 63);
        float p1 = __shfl(acc[i][1], (lane + 16) & 63);
        float p2 = __shfl(acc[i][2], (lane + 16) & 63);
        float p3 = __shfl(acc[i][3], (lane + 16) & 63);
        if (tx < 16 && n < N) {
            half8 v;
            v[0] = (_Float16)acc[i][0]; v[1] = (_Float16)p0;
            v[2] = (_Float16)acc[i][1]; v[3] = (_Float16)p1;
            v[4] = (_Float16)acc[i][2]; v[5] = (_Float16)p2;
            v[6] = (_Float16)acc[i][3]; v[7] = (_Float16)p3;
            *(half8*)&xlh[n * HC + tx * 8] = v;
        }
        float ps = acc[i][0] * vs.x + acc[i][1] * vs.y + acc[i][2] * vs.z + acc[i][3] * vs.w;
        float pd = acc[i][0] * vd.x + acc[i][1] * vd.y + acc[i][2] * vd.z + acc[i][3] * vd.w;
        #pragma unroll
        for (int off = 8; off >= 1; off >>= 1) {
            ps += __shfl_down(ps, off, 16);
            pd += __shfl_down(pd, off, 16);
        }
        if ((tx & 15) == 0 && n < N) {
            int hh = tx >> 4;
            a_s[(size_t)n * 2 + hh] = ps;
            a_d[(size_t)n * 2 + hh] = pd;
        }
    }
}

// ---------------- Edge softmax + aggregate ----------------------------------
// 4 nodes per wave (16 lanes each), width-16 butterflies; per-edge (src, w)
// packed 8B staged in LDS; aggregation = 1 broadcast ds_read_b64 per edge.
// Fallback (any deg>16 in the wave): 64-wide strided path per node.
__global__ __launch_bounds__(256) void k_edge(
    const int* __restrict__ csr_row, const int* __restrict__ csr_src,
    const float* __restrict__ a_s, const float* __restrict__ a_d,
    const _Float16* __restrict__ xlh, const float* __restrict__ bias,
    float* __restrict__ out, int N, int t)
{
    __shared__ int2 edata[16][16];   // [node_local][edge_j] = {src, half2(w0,w1)}

    int tid  = threadIdx.x;
    int lane = tid & 63;
    int wid  = tid >> 6;
    int grp  = lane >> 4;    // 0..3: node slot within wave
    int gl   = lane & 15;    // lane within group

    int nodeBlock0 = blockIdx.x * 16;
    int node = nodeBlock0 + wid * 4 + grp;
    bool nvalid = node < N;

    int beg = 0, end = 0;
    if (nvalid) { beg = csr_row[node]; end = csr_row[node + 1]; }
    int deg = end - beg;

    float bs = bias[lane];

    if (__ballot(deg > 16) == 0ull) {
        // ---- fast path: deg <= 16 for all 4 nodes of this wave ----
        float2 adv = make_float2(0.f, 0.f);
        if (nvalid) adv = *(const float2*)&a_d[(size_t)node * 2];

        int e = beg + gl;
        bool ev = nvalid && (e < end);
        int s = ev ? csr_src[e] : 0;
        float e0 = -1e30f, e1 = -1e30f;
        if (ev) {
            float2 asv = *(const float2*)&a_s[(size_t)s * 2];
            e0 = asv.x + adv.x;
            e1 = asv.y + adv.y;
            e0 = e0 > 0.f ? e0 : NEG_SLOPE * e0;
            e1 = e1 > 0.f ? e1 : NEG_SLOPE * e1;
        }
        // width-16 max butterfly (xor offsets stay inside the 16-lane group)
        float m0 = e0, m1 = e1;
        #pragma unroll
        for (int off = 8; off >= 1; off >>= 1) {
            m0 = fmaxf(m0, __shfl_xor(m0, off));
            m1 = fmaxf(m1, __shfl_xor(m1, off));
        }
        float x0 = ev ? __expf(e0 - m0) : 0.f;
        float x1 = ev ? __expf(e1 - m1) : 0.f;
        float d0 = x0, d1 = x1;
        #pragma unroll
        for (int off = 8; off >= 1; off >>= 1) {
            d0 += __shfl_xor(d0, off);
            d1 += __shfl_xor(d1, off);
        }
        float w0 = x0 * (0.5f / d0);   // 0.5 = head-mean
        float w1 = x1 * (0.5f / d1);

        if (ev) {
            union { uint u; _Float16 h[2]; } cv;
            cv.h[0] = (_Float16)w0;
            cv.h[1] = (_Float16)w1;
            edata[wid * 4 + grp][gl] = make_int2(s, (int)cv.u);
        }
        // wave-synchronous: same wave wrote the rows it reads below

        #pragma unroll
        for (int k = 0; k < 4; k++) {
            int nk = nodeBlock0 + wid * 4 + k;
            if (nk >= N) continue;
            int dk = __shfl(deg, wid * 64 - wid * 64 + k * 16); // lane k*16 of this wave
            float a0 = 0.f, a1 = 0.f;
            const int2* row = edata[wid * 4 + k];
            for (int j = 0; j < dk; j++) {
                int2 ew = row[j];                 // broadcast LDS read
                union { uint u; _Float16 h[2]; } cv;
                cv.u = (uint)ew.y;
                half2v v = *(const half2v*)&xlh[(size_t)ew.x * HC + lane * 2];
                a0 = fmaf((float)cv.h[0], (float)v.x, a0);
                a1 = fmaf((float)cv.h[1], (float)v.y, a1);
            }
            float acc = a0 + a1 + bs;
            float o = acc > 0.f ? acc : expm1f(acc);
            out[((size_t)nk * T_STEPS + t) * C_OUT + lane] = o;
        }
    } else {
        // ---- generic path: 64-wide strided per node, 4 nodes sequentially ----
        #pragma unroll
        for (int k = 0; k < 4; k++) {
            int nk = nodeBlock0 + wid * 4 + k;
            if (nk >= N) continue;
            int bk = __shfl(beg, k * 16);
            int ek = __shfl(end, k * 16);
            float2 adv = *(const float2*)&a_d[(size_t)nk * 2];

            float m0 = -1e30f, m1 = -1e30f;
            for (int e = bk + lane; e < ek; e += 64) {
                int s = csr_src[e];
                float2 asv = *(const float2*)&a_s[(size_t)s * 2];
                float e0 = asv.x + adv.x, e1 = asv.y + adv.y;
                e0 = e0 > 0.f ? e0 : NEG_SLOPE * e0;
                e1 = e1 > 0.f ? e1 : NEG_SLOPE * e1;
                m0 = fmaxf(m0, e0); m1 = fmaxf(m1, e1);
            }
            #pragma unroll
            for (int off = 32; off >= 1; off >>= 1) {
                m0 = fmaxf(m0, __shfl_xor(m0, off));
                m1 = fmaxf(m1, __shfl_xor(m1, off));
            }
            float d0 = 0.f, d1 = 0.f;
            for (int e = bk + lane; e < ek; e += 64) {
                int s = csr_src[e];
                float2 asv = *(const float2*)&a_s[(size_t)s * 2];
                float e0 = asv.x + adv.x, e1 = asv.y + adv.y;
                e0 = e0 > 0.f ? e0 : NEG_SLOPE * e0;
                e1 = e1 > 0.f ? e1 : NEG_SLOPE * e1;
                d0 += __expf(e0 - m0); d1 += __expf(e1 - m1);
            }
            #pragma unroll
            for (int off = 32; off >= 1; off >>= 1) {
                d0 += __shfl_xor(d0, off);
                d1 += __shfl_xor(d1, off);
            }
            float r0 = 0.5f / d0, r1 = 0.5f / d1;

            float a0 = 0.f, a1 = 0.f;
            for (int base = bk; base < ek; base += 64) {
                int e = base + lane;
                int cnt = min(64, ek - base);
                int s = 0; float w0 = 0.f, w1 = 0.f;
                if (e < ek) {
                    s = csr_src[e];
                    float2 asv = *(const float2*)&a_s[(size_t)s * 2];
                    float e0 = asv.x + adv.x, e1 = asv.y + adv.y;
                    e0 = e0 > 0.f ? e0 : NEG_SLOPE * e0;
                    e1 = e1 > 0.f ? e1 : NEG_SLOPE * e1;
                    w0 = __expf(e0 - m0) * r0;
                    w1 = __expf(e1 - m1) * r1;
                }
                for (int j = 0; j < cnt; j++) {
                    int sj = __shfl(s, j);
                    float w0j = __shfl(w0, j);
                    float w1j = __shfl(w1, j);
                    half2v v = *(const half2v*)&xlh[(size_t)sj * HC + lane * 2];
                    a0 = fmaf(w0j, (float)v.x, a0);
                    a1 = fmaf(w1j, (float)v.y, a1);
                }
            }
            float acc = a0 + a1 + bs;
            float o = acc > 0.f ? acc : expm1f(acc);
            out[((size_t)nk * T_STEPS + t) * C_OUT + lane] = o;
        }
    }
}

// ---------------- launcher ----------------
extern "C" void kernel_launch(void* const* d_in, const int* in_sizes, int n_in,
                              void* d_out, int out_size, void* d_ws, size_t ws_size,
                              hipStream_t stream)
{
    const float* h       = (const float*)d_in[0];
    const int*   src     = (const int*)d_in[1];
    const int*   dst     = (const int*)d_in[2];
    const float* W       = (const float*)d_in[3];
    const float* att_src = (const float*)d_in[4];
    const float* att_dst = (const float*)d_in[5];
    const float* bias    = (const float*)d_in[6];
    float* out = (float*)d_out;

    int N = in_sizes[0] / (T_STEPS * F_IN);
    int E = in_sizes[1];

    char* wsb = (char*)d_ws;
    size_t off = 0;
    auto alloc = [&](size_t bytes) -> char* {
        off = (off + 255) & ~(size_t)255;
        char* p = wsb + off;
        off += bytes;
        return p;
    };

    int* csr_row = (int*)alloc((size_t)(N + 1) * sizeof(int));
    int* cursor  = (int*)alloc((size_t)N * sizeof(int));
    int* bsum    = (int*)alloc(1024 * sizeof(int));
    int* csr_src = (int*)alloc((size_t)E * sizeof(int));
    float* a_s   = (float*)alloc((size_t)N * 2 * sizeof(float));
    float* a_d   = (float*)alloc((size_t)N * 2 * sizeof(float));
    _Float16* xlh = (_Float16*)alloc((size_t)N * HC * sizeof(_Float16));

    int nb = (N + 255) / 256;
    k_zero_i32<<<(N + 1 + 255) / 256, 256, 0, stream>>>(csr_row, N + 1);
    k_count<<<(E + 255) / 256, 256, 0, stream>>>(dst, csr_row, E);
    k_scan1<<<nb, 256, 0, stream>>>(csr_row, bsum, N);
    k_scan2<<<1, 256, 0, stream>>>(bsum, nb);
    k_scan3<<<nb, 256, 0, stream>>>(csr_row, bsum, cursor, N, E);
    k_fill<<<(E + 255) / 256, 256, 0, stream>>>(src, dst, cursor, csr_src, E);

    for (int t = 0; t < T_STEPS; t++) {
        k_gemm<<<(N + 63) / 64, 256, 0, stream>>>(h, W, att_src, att_dst,
                                                  xlh, a_s, a_d, N, t);
        k_edge<<<(N + 15) / 16, 256, 0, stream>>>(csr_row, csr_src, a_s, a_d,
                                                  xlh, bias, out, N, t);
    }
}

// Round 4
// 458.757 us; speedup vs baseline: 1.8874x; 1.6047x over previous
//
#include <hip/hip_runtime.h>
#include <hip/hip_bf16.h>
#include <math.h>

#define T_STEPS 8
#define F_IN 64
#define HC 128        // H*C = 2*64
#define C_OUT 64
#define NEG_SLOPE 0.2f

typedef _Float16 half8 __attribute__((ext_vector_type(8)));
typedef _Float16 half2v __attribute__((ext_vector_type(2)));

// ---------------- CSR build ----------------
__global__ void k_zero_i32(int* p, int n) {
    int i = blockIdx.x * blockDim.x + threadIdx.x;
    if (i < n) p[i] = 0;
}

__global__ void k_count(const int* __restrict__ dst, int* __restrict__ cnt, int E) {
    int e = blockIdx.x * blockDim.x + threadIdx.x;
    if (e < E) atomicAdd(&cnt[dst[e]], 1);
}

__global__ void k_scan1(int* data, int* bsum, int n) {
    __shared__ int tmp[256];
    int tid = threadIdx.x;
    int i = blockIdx.x * 256 + tid;
    int v = (i < n) ? data[i] : 0;
    tmp[tid] = v; __syncthreads();
    for (int off = 1; off < 256; off <<= 1) {
        int x = (tid >= off) ? tmp[tid - off] : 0;
        __syncthreads();
        tmp[tid] += x;
        __syncthreads();
    }
    if (i < n) data[i] = tmp[tid] - v;   // exclusive
    if (tid == 255) bsum[blockIdx.x] = tmp[255];
}

__global__ void k_scan2(int* bsum, int nb) {  // nb <= 256
    __shared__ int tmp[256];
    int tid = threadIdx.x;
    int v = (tid < nb) ? bsum[tid] : 0;
    tmp[tid] = v; __syncthreads();
    for (int off = 1; off < 256; off <<= 1) {
        int x = (tid >= off) ? tmp[tid - off] : 0;
        __syncthreads();
        tmp[tid] += x;
        __syncthreads();
    }
    if (tid < nb) bsum[tid] = tmp[tid] - v;
}

__global__ void k_scan3(int* data, const int* __restrict__ bsum, int* cursor, int n, int total) {
    int i = blockIdx.x * 256 + threadIdx.x;
    if (i < n) {
        int v = data[i] + bsum[i >> 8];
        data[i] = v;
        cursor[i] = v;
    }
    if (i == 0) data[n] = total;
}

__global__ void k_fill(const int* __restrict__ src, const int* __restrict__ dst,
                       int* __restrict__ cursor, int* __restrict__ csr_src, int E) {
    int e = blockIdx.x * blockDim.x + threadIdx.x;
    if (e < E) {
        int d = dst[e];
        int pos = atomicAdd(&cursor[d], 1);
        csr_src[pos] = src[e];
    }
}

// ---------------- GEMM: xl = x_t @ W (fp16 head-interleaved out) + scores ----
// blockIdx.y = timestep. xlh slice t: xlh + t*N*HC.
__global__ __launch_bounds__(256) void k_gemm(
    const float* __restrict__ h, const float* __restrict__ W,
    const float* __restrict__ att_src, const float* __restrict__ att_dst,
    _Float16* __restrict__ xlh, float* __restrict__ a_s, float* __restrict__ a_d,
    int N)
{
    __shared__ float sW[F_IN * HC];
    __shared__ float sX[F_IN * 64];   // transposed: sX[f*64 + node_local]
    __shared__ float sAS[HC], sAD[HC];

    int tid = threadIdx.x;
    int t = blockIdx.y;
    int node0 = blockIdx.x * 64;
    _Float16* xlt = xlh + (size_t)t * N * HC;
    float* ast = a_s + (size_t)t * N * 2;
    float* adt = a_d + (size_t)t * N * 2;

    for (int i = tid * 4; i < F_IN * HC; i += 1024)
        *(float4*)&sW[i] = *(const float4*)&W[i];
    if (tid < HC) { sAS[tid] = att_src[tid]; sAD[tid] = att_dst[tid]; }

    for (int u = tid; u < 64 * 16; u += 256) {
        int nl = u >> 4;
        int f4 = u & 15;
        int n = node0 + nl;
        float4 v = make_float4(0.f, 0.f, 0.f, 0.f);
        if (n < N) v = *(const float4*)&h[(n * T_STEPS + t) * F_IN + f4 * 4];
        sX[(f4 * 4 + 0) * 64 + nl] = v.x;
        sX[(f4 * 4 + 1) * 64 + nl] = v.y;
        sX[(f4 * 4 + 2) * 64 + nl] = v.z;
        sX[(f4 * 4 + 3) * 64 + nl] = v.w;
    }
    __syncthreads();

    int tx = tid & 31;
    int ty = tid >> 5;
    int lane = tid & 63;
    float acc[8][4];
    #pragma unroll
    for (int i = 0; i < 8; i++)
        #pragma unroll
        for (int j = 0; j < 4; j++) acc[i][j] = 0.f;

    #pragma unroll 4
    for (int f = 0; f < F_IN; f++) {
        float4 wv = *(float4*)&sW[f * HC + tx * 4];
        float4 xa = *(float4*)&sX[f * 64 + ty * 8];
        float4 xb = *(float4*)&sX[f * 64 + ty * 8 + 4];
        float xs[8] = {xa.x, xa.y, xa.z, xa.w, xb.x, xb.y, xb.z, xb.w};
        #pragma unroll
        for (int i = 0; i < 8; i++) {
            acc[i][0] += xs[i] * wv.x;
            acc[i][1] += xs[i] * wv.y;
            acc[i][2] += xs[i] * wv.z;
            acc[i][3] += xs[i] * wv.w;
        }
    }

    float4 vs = *(float4*)&sAS[tx * 4];
    float4 vd = *(float4*)&sAD[tx * 4];
    #pragma unroll
    for (int i = 0; i < 8; i++) {
        int n = node0 + ty * 8 + i;
        float p0 = __shfl(acc[i][0], (lane + 16) & 63);
        float p1 = __shfl(acc[i][1], (lane + 16) & 63);
        float p2 = __shfl(acc[i][2], (lane + 16) & 63);
        float p3 = __shfl(acc[i][3], (lane + 16) & 63);
        if (tx < 16 && n < N) {
            half8 v;
            v[0] = (_Float16)acc[i][0]; v[1] = (_Float16)p0;
            v[2] = (_Float16)acc[i][1]; v[3] = (_Float16)p1;
            v[4] = (_Float16)acc[i][2]; v[5] = (_Float16)p2;
            v[6] = (_Float16)acc[i][3]; v[7] = (_Float16)p3;
            *(half8*)&xlt[(size_t)n * HC + tx * 8] = v;
        }
        float ps = acc[i][0] * vs.x + acc[i][1] * vs.y + acc[i][2] * vs.z + acc[i][3] * vs.w;
        float pd = acc[i][0] * vd.x + acc[i][1] * vd.y + acc[i][2] * vd.z + acc[i][3] * vd.w;
        #pragma unroll
        for (int off = 8; off >= 1; off >>= 1) {
            ps += __shfl_down(ps, off, 16);
            pd += __shfl_down(pd, off, 16);
        }
        if ((tx & 15) == 0 && n < N) {
            int hh = tx >> 4;
            ast[(size_t)n * 2 + hh] = ps;
            adt[(size_t)n * 2 + hh] = pd;
        }
    }
}

// ---------------- Edge softmax + aggregate ----------------------------------
// blockIdx.y = timestep. 4 nodes per wave (16 lanes each), width-16 butterflies.
// Edge descriptors {src, half2(w0,w1)} staged in LDS, padded to mult of 4 with
// zero-weight entries; aggregation unrolled x4 -> 4 independent gathers in
// flight (MLP), instead of one dependent chain.
__global__ __launch_bounds__(256) void k_edge(
    const int* __restrict__ csr_row, const int* __restrict__ csr_src,
    const float* __restrict__ a_s, const float* __restrict__ a_d,
    const _Float16* __restrict__ xlh, const float* __restrict__ bias,
    float* __restrict__ out, int N)
{
    __shared__ int2 edata[16][16];   // [node_local][edge_j] = {src, half2(w0,w1)}

    int tid  = threadIdx.x;
    int lane = tid & 63;
    int wid  = tid >> 6;
    int grp  = lane >> 4;    // 0..3: node slot within wave
    int gl   = lane & 15;    // lane within group
    int t = blockIdx.y;
    const _Float16* xlt = xlh + (size_t)t * N * HC;
    const float* ast = a_s + (size_t)t * N * 2;
    const float* adt = a_d + (size_t)t * N * 2;

    int nodeBlock0 = blockIdx.x * 16;
    int node = nodeBlock0 + wid * 4 + grp;
    bool nvalid = node < N;

    int beg = 0, end = 0;
    if (nvalid) { beg = csr_row[node]; end = csr_row[node + 1]; }
    int deg = end - beg;

    float bs = bias[lane];

    if (__ballot(deg > 16) == 0ull) {
        // ---- fast path: deg <= 16 for all 4 nodes of this wave ----
        float2 adv = make_float2(0.f, 0.f);
        if (nvalid) adv = *(const float2*)&adt[(size_t)node * 2];

        int e = beg + gl;
        bool ev = nvalid && (e < end);
        int s = ev ? csr_src[e] : 0;
        float e0 = -1e30f, e1 = -1e30f;
        if (ev) {
            float2 asv = *(const float2*)&ast[(size_t)s * 2];
            e0 = asv.x + adv.x;
            e1 = asv.y + adv.y;
            e0 = e0 > 0.f ? e0 : NEG_SLOPE * e0;
            e1 = e1 > 0.f ? e1 : NEG_SLOPE * e1;
        }
        float m0 = e0, m1 = e1;
        #pragma unroll
        for (int off = 8; off >= 1; off >>= 1) {
            m0 = fmaxf(m0, __shfl_xor(m0, off));
            m1 = fmaxf(m1, __shfl_xor(m1, off));
        }
        float x0 = ev ? __expf(e0 - m0) : 0.f;
        float x1 = ev ? __expf(e1 - m1) : 0.f;
        float d0 = x0, d1 = x1;
        #pragma unroll
        for (int off = 8; off >= 1; off >>= 1) {
            d0 += __shfl_xor(d0, off);
            d1 += __shfl_xor(d1, off);
        }
        float w0 = x0 * (0.5f / d0);   // 0.5 = head-mean
        float w1 = x1 * (0.5f / d1);

        // all 16 slots written: invalid lanes write zero-weight entries (src 0)
        union { uint u; _Float16 hh[2]; } cw;
        cw.hh[0] = ev ? (_Float16)w0 : (_Float16)0.f;
        cw.hh[1] = ev ? (_Float16)w1 : (_Float16)0.f;
        edata[wid * 4 + grp][gl] = make_int2(ev ? s : 0, (int)cw.u);
        // wave-synchronous: same wave wrote the rows it reads below

        #pragma unroll
        for (int k = 0; k < 4; k++) {
            int nk = nodeBlock0 + wid * 4 + k;
            if (nk >= N) continue;
            int dk = __shfl(deg, k * 16);
            int dkr = (dk + 3) & ~3;          // padded entries have w=0
            float a0 = 0.f, a1 = 0.f;
            const int2* row = edata[wid * 4 + k];
            for (int j = 0; j < dkr; j += 4) {
                int4 p = *(const int4*)&row[j];       // edges j, j+1
                int4 q = *(const int4*)&row[j + 2];   // edges j+2, j+3
                half2v v0 = *(const half2v*)&xlt[(size_t)p.x * HC + lane * 2];
                half2v v1 = *(const half2v*)&xlt[(size_t)p.z * HC + lane * 2];
                half2v v2 = *(const half2v*)&xlt[(size_t)q.x * HC + lane * 2];
                half2v v3 = *(const half2v*)&xlt[(size_t)q.z * HC + lane * 2];
                union { uint u; _Float16 hh[2]; } c0, c1, c2, c3;
                c0.u = (uint)p.y; c1.u = (uint)p.w;
                c2.u = (uint)q.y; c3.u = (uint)q.w;
                a0 = fmaf((float)c0.hh[0], (float)v0.x, a0);
                a1 = fmaf((float)c0.hh[1], (float)v0.y, a1);
                a0 = fmaf((float)c1.hh[0], (float)v1.x, a0);
                a1 = fmaf((float)c1.hh[1], (float)v1.y, a1);
                a0 = fmaf((float)c2.hh[0], (float)v2.x, a0);
                a1 = fmaf((float)c2.hh[1], (float)v2.y, a1);
                a0 = fmaf((float)c3.hh[0], (float)v3.x, a0);
                a1 = fmaf((float)c3.hh[1], (float)v3.y, a1);
            }
            float acc = a0 + a1 + bs;
            float o = acc > 0.f ? acc : expm1f(acc);
            out[((size_t)nk * T_STEPS + t) * C_OUT + lane] = o;
        }
    } else {
        // ---- generic path: 64-wide strided per node, 4 nodes sequentially ----
        #pragma unroll
        for (int k = 0; k < 4; k++) {
            int nk = nodeBlock0 + wid * 4 + k;
            if (nk >= N) continue;
            int bk = __shfl(beg, k * 16);
            int ek = __shfl(end, k * 16);
            float2 adv = *(const float2*)&adt[(size_t)nk * 2];

            float m0 = -1e30f, m1 = -1e30f;
            for (int e = bk + lane; e < ek; e += 64) {
                int s = csr_src[e];
                float2 asv = *(const float2*)&ast[(size_t)s * 2];
                float e0 = asv.x + adv.x, e1 = asv.y + adv.y;
                e0 = e0 > 0.f ? e0 : NEG_SLOPE * e0;
                e1 = e1 > 0.f ? e1 : NEG_SLOPE * e1;
                m0 = fmaxf(m0, e0); m1 = fmaxf(m1, e1);
            }
            #pragma unroll
            for (int off = 32; off >= 1; off >>= 1) {
                m0 = fmaxf(m0, __shfl_xor(m0, off));
                m1 = fmaxf(m1, __shfl_xor(m1, off));
            }
            float d0 = 0.f, d1 = 0.f;
            for (int e = bk + lane; e < ek; e += 64) {
                int s = csr_src[e];
                float2 asv = *(const float2*)&ast[(size_t)s * 2];
                float e0 = asv.x + adv.x, e1 = asv.y + adv.y;
                e0 = e0 > 0.f ? e0 : NEG_SLOPE * e0;
                e1 = e1 > 0.f ? e1 : NEG_SLOPE * e1;
                d0 += __expf(e0 - m0); d1 += __expf(e1 - m1);
            }
            #pragma unroll
            for (int off = 32; off >= 1; off >>= 1) {
                d0 += __shfl_xor(d0, off);
                d1 += __shfl_xor(d1, off);
            }
            float r0 = 0.5f / d0, r1 = 0.5f / d1;

            float a0 = 0.f, a1 = 0.f;
            for (int base = bk; base < ek; base += 64) {
                int e = base + lane;
                int cnt = min(64, ek - base);
                int s = 0; float w0 = 0.f, w1 = 0.f;
                if (e < ek) {
                    s = csr_src[e];
                    float2 asv = *(const float2*)&ast[(size_t)s * 2];
                    float e0 = asv.x + adv.x, e1 = asv.y + adv.y;
                    e0 = e0 > 0.f ? e0 : NEG_SLOPE * e0;
                    e1 = e1 > 0.f ? e1 : NEG_SLOPE * e1;
                    w0 = __expf(e0 - m0) * r0;
                    w1 = __expf(e1 - m1) * r1;
                }
                for (int j = 0; j < cnt; j++) {
                    int sj = __shfl(s, j);
                    float w0j = __shfl(w0, j);
                    float w1j = __shfl(w1, j);
                    half2v v = *(const half2v*)&xlt[(size_t)sj * HC + lane * 2];
                    a0 = fmaf(w0j, (float)v.x, a0);
                    a1 = fmaf(w1j, (float)v.y, a1);
                }
            }
            float acc = a0 + a1 + bs;
            float o = acc > 0.f ? acc : expm1f(acc);
            out[((size_t)nk * T_STEPS + t) * C_OUT + lane] = o;
        }
    }
}

// ---------------- launcher ----------------
extern "C" void kernel_launch(void* const* d_in, const int* in_sizes, int n_in,
                              void* d_out, int out_size, void* d_ws, size_t ws_size,
                              hipStream_t stream)
{
    const float* h       = (const float*)d_in[0];
    const int*   src     = (const int*)d_in[1];
    const int*   dst     = (const int*)d_in[2];
    const float* W       = (const float*)d_in[3];
    const float* att_src = (const float*)d_in[4];
    const float* att_dst = (const float*)d_in[5];
    const float* bias    = (const float*)d_in[6];
    float* out = (float*)d_out;

    int N = in_sizes[0] / (T_STEPS * F_IN);
    int E = in_sizes[1];

    char* wsb = (char*)d_ws;
    size_t off = 0;
    auto alloc = [&](size_t bytes) -> char* {
        off = (off + 255) & ~(size_t)255;
        char* p = wsb + off;
        off += bytes;
        return p;
    };

    int* csr_row = (int*)alloc((size_t)(N + 1) * sizeof(int));
    int* cursor  = (int*)alloc((size_t)N * sizeof(int));
    int* bsum    = (int*)alloc(1024 * sizeof(int));
    int* csr_src = (int*)alloc((size_t)E * sizeof(int));
    float* a_s   = (float*)alloc((size_t)T_STEPS * N * 2 * sizeof(float));
    float* a_d   = (float*)alloc((size_t)T_STEPS * N * 2 * sizeof(float));
    _Float16* xlh = (_Float16*)alloc((size_t)T_STEPS * N * HC * sizeof(_Float16));
    // total ~110 MB; all-t fp16 xlh (102 MB) fits L3 (256 MB)

    int nb = (N + 255) / 256;
    k_zero_i32<<<(N + 1 + 255) / 256, 256, 0, stream>>>(csr_row, N + 1);
    k_count<<<(E + 255) / 256, 256, 0, stream>>>(dst, csr_row, E);
    k_scan1<<<nb, 256, 0, stream>>>(csr_row, bsum, N);
    k_scan2<<<1, 256, 0, stream>>>(bsum, nb);
    k_scan3<<<nb, 256, 0, stream>>>(csr_row, bsum, cursor, N, E);
    k_fill<<<(E + 255) / 256, 256, 0, stream>>>(src, dst, cursor, csr_src, E);

    dim3 gg((N + 63) / 64, T_STEPS);
    k_gemm<<<gg, 256, 0, stream>>>(h, W, att_src, att_dst, xlh, a_s, a_d, N);
    dim3 ge((N + 15) / 16, T_STEPS);
    k_edge<<<ge, 256, 0, stream>>>(csr_row, csr_src, a_s, a_d, xlh, bias, out, N);
}